// Round 8
// baseline (32.230 us; speedup 1.0000x reference)
//
#include <hip/hip_runtime.h>

#define NPIX  (16 * 768 * 768)   // 9437184 pixels per map
#define NG    (NPIX / 4)         // 2359296 groups of 4 pixels
#define NBLK  2304               // 9 blocks per CU
#define NTHR  (NBLK * 256)       // 589824 threads
#define GPT   (NG / NTHR)        // 4 groups per thread, exact

typedef float f32x4 __attribute__((ext_vector_type(4)));

// d_ws layout: f32x4 partial[NBLK] = {sum_char, cnt_char, sum_aff, cnt_aff}

__global__ __launch_bounds__(256) void craft_reduce(
    const f32x4* __restrict__ out4,   // [2*NG] : (c,a,c,a) per vec4
    const f32x4* __restrict__ cmap4,  // [NG]
    const f32x4* __restrict__ amap4,  // [NG]
    f32x4* __restrict__ partial)      // [NBLK]
{
    const int tid = blockIdx.x * blockDim.x + threadIdx.x;

    float sum_c = 0.f, cnt_c = 0.f, sum_a = 0.f, cnt_a = 0.f;

    #pragma unroll
    for (int k = 0; k < GPT; ++k) {
        const int g = tid + k * NTHR;
        f32x4 o0 = out4[2 * g];      // c0 a0 c1 a1
        f32x4 o1 = out4[2 * g + 1];  // c2 a2 c3 a3
        f32x4 ct = cmap4[g];         // t0 t1 t2 t3
        f32x4 at = amap4[g];         // s0 s1 s2 s3

        #define ACC(p, t, S, C)                                   \
            {                                                     \
                float d_ = (p) - (t);                             \
                bool pos_ = (t) >= 0.1f;                          \
                S += (pos_ || (t) <= 0.0f) ? d_ * d_ : 0.f;       \
                C += pos_ ? 1.f : 0.f;                            \
            }

        ACC(o0.x, ct.x, sum_c, cnt_c); ACC(o0.y, at.x, sum_a, cnt_a);
        ACC(o0.z, ct.y, sum_c, cnt_c); ACC(o0.w, at.y, sum_a, cnt_a);
        ACC(o1.x, ct.z, sum_c, cnt_c); ACC(o1.y, at.z, sum_a, cnt_a);
        ACC(o1.z, ct.w, sum_c, cnt_c); ACC(o1.w, at.w, sum_a, cnt_a);
        #undef ACC
    }

    // wave(64) down-reduce
    #pragma unroll
    for (int off = 32; off > 0; off >>= 1) {
        sum_c += __shfl_down(sum_c, off, 64);
        cnt_c += __shfl_down(cnt_c, off, 64);
        sum_a += __shfl_down(sum_a, off, 64);
        cnt_a += __shfl_down(cnt_a, off, 64);
    }

    __shared__ float red[4][4];
    const int wave = threadIdx.x >> 6;
    const int lane = threadIdx.x & 63;
    if (lane == 0) {
        red[wave][0] = sum_c;
        red[wave][1] = cnt_c;
        red[wave][2] = sum_a;
        red[wave][3] = cnt_a;
    }
    __syncthreads();

    if (threadIdx.x == 0) {
        float s0 = 0.f, s1 = 0.f, s2 = 0.f, s3 = 0.f;
        #pragma unroll
        for (int w = 0; w < 4; ++w) {
            s0 += red[w][0];
            s1 += red[w][1];
            s2 += red[w][2];
            s3 += red[w][3];
        }
        f32x4 p = {s0, s1, s2, s3};
        partial[blockIdx.x] = p;   // NO atomics
    }
}

__global__ __launch_bounds__(256) void craft_final(
    const f32x4* __restrict__ partial, float* __restrict__ out)
{
    float s0 = 0.f, s1 = 0.f, s2 = 0.f, s3 = 0.f;
    for (int i = threadIdx.x; i < NBLK; i += 256) {   // 9 iters exact
        f32x4 p = partial[i];
        s0 += p.x; s1 += p.y; s2 += p.z; s3 += p.w;
    }

    #pragma unroll
    for (int off = 32; off > 0; off >>= 1) {
        s0 += __shfl_down(s0, off, 64);
        s1 += __shfl_down(s1, off, 64);
        s2 += __shfl_down(s2, off, 64);
        s3 += __shfl_down(s3, off, 64);
    }

    __shared__ float red[4][4];
    const int wave = threadIdx.x >> 6;
    const int lane = threadIdx.x & 63;
    if (lane == 0) {
        red[wave][0] = s0; red[wave][1] = s1;
        red[wave][2] = s2; red[wave][3] = s3;
    }
    __syncthreads();

    if (threadIdx.x == 0) {
        float a0 = red[0][0] + red[1][0] + red[2][0] + red[3][0];
        float a1 = red[0][1] + red[1][1] + red[2][1] + red[3][1];
        float a2 = red[0][2] + red[1][2] + red[2][2] + red[3][2];
        float a3 = red[0][3] + red[1][3] + red[2][3] + red[3][3];
        const float n = (float)NPIX;
        out[0] = (2.f * (a0 / (a1 + n)) + a2 / (a3 + n)) * 100.f;
    }
}

extern "C" void kernel_launch(void* const* d_in, const int* in_sizes, int n_in,
                              void* d_out, int out_size, void* d_ws, size_t ws_size,
                              hipStream_t stream)
{
    const f32x4* out4  = (const f32x4*)d_in[0];  // (16,768,768,2)
    const f32x4* cmap4 = (const f32x4*)d_in[1];  // (16,768,768)
    const f32x4* amap4 = (const f32x4*)d_in[2];  // (16,768,768)
    float*  result  = (float*)d_out;
    f32x4*  partial = (f32x4*)d_ws;              // 2304 * 16 B = 36 KB

    craft_reduce<<<dim3(NBLK), dim3(256), 0, stream>>>(out4, cmap4, amap4, partial);
    craft_final<<<dim3(1), dim3(256), 0, stream>>>(partial, result);
}

// Round 9
// 29.846 us; speedup vs baseline: 1.0799x; 1.0799x over previous
//
#include <hip/hip_runtime.h>

#define NPIX  (16 * 768 * 768)   // 9437184 pixels per map
#define NG    (NPIX / 4)         // 2359296 groups of 4 pixels
#define NBLK  1536               // 6 blocks/CU on 256 CUs -> all resident, no tail round
#define NTHR  (NBLK * 256)       // 393216 threads
#define GPT   (NG / NTHR)        // 6 groups per thread, exact

typedef float f32x4 __attribute__((ext_vector_type(4)));

// d_ws layout: f32x4 partial[NBLK] = {sum_char, cnt_char, sum_aff, cnt_aff}

__global__ __launch_bounds__(256) void craft_reduce(
    const f32x4* __restrict__ out4,   // [2*NG] : (c,a,c,a) per vec4
    const f32x4* __restrict__ cmap4,  // [NG]
    const f32x4* __restrict__ amap4,  // [NG]
    f32x4* __restrict__ partial)      // [NBLK]
{
    const int tid = blockIdx.x * blockDim.x + threadIdx.x;

    float sum_c = 0.f, cnt_c = 0.f, sum_a = 0.f, cnt_a = 0.f;

    #pragma unroll
    for (int k = 0; k < GPT; ++k) {
        const int g = tid + k * NTHR;
        f32x4 o0 = __builtin_nontemporal_load(&out4[2 * g]);     // c0 a0 c1 a1
        f32x4 o1 = __builtin_nontemporal_load(&out4[2 * g + 1]); // c2 a2 c3 a3
        f32x4 ct = __builtin_nontemporal_load(&cmap4[g]);        // t0 t1 t2 t3
        f32x4 at = __builtin_nontemporal_load(&amap4[g]);        // s0 s1 s2 s3

        #define ACC(p, t, S, C)                                   \
            {                                                     \
                float d_ = (p) - (t);                             \
                bool pos_ = (t) >= 0.1f;                          \
                S += (pos_ || (t) <= 0.0f) ? d_ * d_ : 0.f;       \
                C += pos_ ? 1.f : 0.f;                            \
            }

        ACC(o0.x, ct.x, sum_c, cnt_c); ACC(o0.y, at.x, sum_a, cnt_a);
        ACC(o0.z, ct.y, sum_c, cnt_c); ACC(o0.w, at.y, sum_a, cnt_a);
        ACC(o1.x, ct.z, sum_c, cnt_c); ACC(o1.y, at.z, sum_a, cnt_a);
        ACC(o1.z, ct.w, sum_c, cnt_c); ACC(o1.w, at.w, sum_a, cnt_a);
        #undef ACC
    }

    // wave(64) down-reduce
    #pragma unroll
    for (int off = 32; off > 0; off >>= 1) {
        sum_c += __shfl_down(sum_c, off, 64);
        cnt_c += __shfl_down(cnt_c, off, 64);
        sum_a += __shfl_down(sum_a, off, 64);
        cnt_a += __shfl_down(cnt_a, off, 64);
    }

    __shared__ float red[4][4];
    const int wave = threadIdx.x >> 6;
    const int lane = threadIdx.x & 63;
    if (lane == 0) {
        red[wave][0] = sum_c;
        red[wave][1] = cnt_c;
        red[wave][2] = sum_a;
        red[wave][3] = cnt_a;
    }
    __syncthreads();

    if (threadIdx.x == 0) {
        float s0 = 0.f, s1 = 0.f, s2 = 0.f, s3 = 0.f;
        #pragma unroll
        for (int w = 0; w < 4; ++w) {
            s0 += red[w][0];
            s1 += red[w][1];
            s2 += red[w][2];
            s3 += red[w][3];
        }
        f32x4 p = {s0, s1, s2, s3};
        partial[blockIdx.x] = p;   // NO atomics
    }
}

__global__ __launch_bounds__(256) void craft_final(
    const f32x4* __restrict__ partial, float* __restrict__ out)
{
    float s0 = 0.f, s1 = 0.f, s2 = 0.f, s3 = 0.f;
    for (int i = threadIdx.x; i < NBLK; i += 256) {   // 6 iters exact
        f32x4 p = partial[i];
        s0 += p.x; s1 += p.y; s2 += p.z; s3 += p.w;
    }

    #pragma unroll
    for (int off = 32; off > 0; off >>= 1) {
        s0 += __shfl_down(s0, off, 64);
        s1 += __shfl_down(s1, off, 64);
        s2 += __shfl_down(s2, off, 64);
        s3 += __shfl_down(s3, off, 64);
    }

    __shared__ float red[4][4];
    const int wave = threadIdx.x >> 6;
    const int lane = threadIdx.x & 63;
    if (lane == 0) {
        red[wave][0] = s0; red[wave][1] = s1;
        red[wave][2] = s2; red[wave][3] = s3;
    }
    __syncthreads();

    if (threadIdx.x == 0) {
        float a0 = red[0][0] + red[1][0] + red[2][0] + red[3][0];
        float a1 = red[0][1] + red[1][1] + red[2][1] + red[3][1];
        float a2 = red[0][2] + red[1][2] + red[2][2] + red[3][2];
        float a3 = red[0][3] + red[1][3] + red[2][3] + red[3][3];
        const float n = (float)NPIX;
        out[0] = (2.f * (a0 / (a1 + n)) + a2 / (a3 + n)) * 100.f;
    }
}

extern "C" void kernel_launch(void* const* d_in, const int* in_sizes, int n_in,
                              void* d_out, int out_size, void* d_ws, size_t ws_size,
                              hipStream_t stream)
{
    const f32x4* out4  = (const f32x4*)d_in[0];  // (16,768,768,2)
    const f32x4* cmap4 = (const f32x4*)d_in[1];  // (16,768,768)
    const f32x4* amap4 = (const f32x4*)d_in[2];  // (16,768,768)
    float*  result  = (float*)d_out;
    f32x4*  partial = (f32x4*)d_ws;              // 1536 * 16 B = 24 KB

    craft_reduce<<<dim3(NBLK), dim3(256), 0, stream>>>(out4, cmap4, amap4, partial);
    craft_final<<<dim3(1), dim3(256), 0, stream>>>(partial, result);
}